// Round 6
// baseline (662.222 us; speedup 1.0000x reference)
//
#include <hip/hip_runtime.h>

// B=8, T=2048, IDIM=512, HDIM=2048, CDIM=64, ENERGY_TH=256
// Device dtypes: all float tensors f32, theta int32.
// d_out = [out f32 8*2048*512 | mask f32 8*2048*2048]
//   - mask region doubles as H scratch (f32, 134MB), overwritten with mask at the end
//   - out  region doubles as Xh/Xl scratch (2x16.78MB f16), overwritten with out at the end
// d_ws usage: Wh 2MB | Wl 2MB | IDX 4.2MB | SRCT 64KB  (~8.3MB total)

typedef _Float16 f16x8 __attribute__((ext_vector_type(8)));
typedef _Float16 f16x4 __attribute__((ext_vector_type(4)));
typedef float    f32x4 __attribute__((ext_vector_type(4)));
typedef unsigned int uint;
typedef unsigned short ushort;

constexpr int Mrows = 16384;   // B*T
constexpr int Kdim  = 512;     // IDIM
constexpr int Ndim  = 2048;    // HDIM

// ---------------------------------------------------------------------------
// K0a: split x (f32) -> xh = f16(x), xl = f16((x - xh)*2048)
// ---------------------------------------------------------------------------
__global__ __launch_bounds__(256) void split_x_kernel(
    const float* __restrict__ x, _Float16* __restrict__ xh, _Float16* __restrict__ xl) {
    int i = blockIdx.x * 256 + threadIdx.x;           // x4 floats
    float4 v = ((const float4*)x)[i];
    f16x4 h, l;
    float vv[4] = {v.x, v.y, v.z, v.w};
#pragma unroll
    for (int j = 0; j < 4; ++j) {
        _Float16 hj = (_Float16)vv[j];
        h[j] = hj;
        l[j] = (_Float16)((vv[j] - (float)hj) * 2048.0f);
    }
    *(f16x4*)(xh + i * 4) = h;
    *(f16x4*)(xl + i * 4) = l;
}

// ---------------------------------------------------------------------------
// K0b: transpose + split W_enc [512][2048] f32 -> Wh/Wl [2048][512] f16
// wh = f16(w*1024), wl = f16((w*1024 - wh)*2048)   (1024 scale avoids f16 denorms)
// ---------------------------------------------------------------------------
__global__ __launch_bounds__(256) void split_w_kernel(
    const float* __restrict__ W, _Float16* __restrict__ Wh, _Float16* __restrict__ Wl) {
    __shared__ float T[32][33];
    int n0 = blockIdx.x * 32, k0 = blockIdx.y * 32;
    int tid = threadIdx.x;
    int c = tid & 31, r0 = tid >> 5;
#pragma unroll
    for (int i = 0; i < 4; ++i) {
        int r = r0 + 8 * i;
        T[r][c] = W[(size_t)(k0 + r) * Ndim + n0 + c];
    }
    __syncthreads();
#pragma unroll
    for (int i = 0; i < 4; ++i) {
        int r = r0 + 8 * i;                 // n-offset within tile
        float ws = T[c][r] * 1024.0f;
        _Float16 wh = (_Float16)ws;
        _Float16 wl = (_Float16)((ws - (float)wh) * 2048.0f);
        size_t o = (size_t)(n0 + r) * Kdim + k0 + c;
        Wh[o] = wh;
        Wl[o] = wl;
    }
}

// ---------------------------------------------------------------------------
// K1: H = x @ W_enc + b_enc, f32-accurate via f16 split MFMA (3 terms).
// A rows [M][K], B^T rows [N][K]. 128x128 tile, BK=32, 4 waves (2x2),
// per-wave 64x64 = 4x4 fragments of 16x16x32.
// h = (P + Q/2048)/1024 + bias,  P=sum xh*wh,  Q=sum(xh*wl + xl*wh)
// ---------------------------------------------------------------------------
#define GBM 128
#define GBN 128
#define GBK 32
#define LDK 40

__global__ __launch_bounds__(256) void gemm_split_kernel(
    const _Float16* __restrict__ Xh, const _Float16* __restrict__ Xl,
    const _Float16* __restrict__ Wh, const _Float16* __restrict__ Wl,
    const float* __restrict__ benc, float* __restrict__ H) {
    __shared__ _Float16 Ah[GBM * LDK], Al[GBM * LDK];
    __shared__ _Float16 Bh[GBN * LDK], Bl[GBN * LDK];
    int tid = threadIdx.x;
    int bn = blockIdx.x, bm = blockIdx.y;
    int wave = tid >> 6, lane = tid & 63;
    int wm = wave >> 1, wn = wave & 1;
    int l15 = lane & 15, lk = (lane >> 4) << 3;

    f32x4 accP[4][4] = {};
    f32x4 accQ[4][4] = {};

    const _Float16* XhB = Xh + (size_t)(bm * GBM) * Kdim;
    const _Float16* XlB = Xl + (size_t)(bm * GBM) * Kdim;
    const _Float16* WhB = Wh + (size_t)(bn * GBN) * Kdim;
    const _Float16* WlB = Wl + (size_t)(bn * GBN) * Kdim;
    int srow = tid >> 1, sc = tid & 1;       // 2 threads per 128-row, 32B each

    for (int k0 = 0; k0 < Kdim; k0 += GBK) {
        int goff = srow * Kdim + k0 + sc * 16;
        int loff = srow * LDK + sc * 16;
        uint4 a0 = ((const uint4*)(XhB + goff))[0];
        uint4 a1 = ((const uint4*)(XhB + goff))[1];
        uint4 b0 = ((const uint4*)(XlB + goff))[0];
        uint4 b1 = ((const uint4*)(XlB + goff))[1];
        uint4 c0 = ((const uint4*)(WhB + goff))[0];
        uint4 c1 = ((const uint4*)(WhB + goff))[1];
        uint4 d0 = ((const uint4*)(WlB + goff))[0];
        uint4 d1 = ((const uint4*)(WlB + goff))[1];
        *(uint4*)&Ah[loff] = a0; *(uint4*)&Ah[loff + 8] = a1;
        *(uint4*)&Al[loff] = b0; *(uint4*)&Al[loff + 8] = b1;
        *(uint4*)&Bh[loff] = c0; *(uint4*)&Bh[loff + 8] = c1;
        *(uint4*)&Bl[loff] = d0; *(uint4*)&Bl[loff + 8] = d1;
        __syncthreads();

        f16x8 ah[4], al8[4], bh8[4], bl8[4];
#pragma unroll
        for (int mf = 0; mf < 4; ++mf) {
            int r = (wm * 64 + mf * 16 + l15) * LDK + lk;
            ah[mf]  = *(const f16x8*)&Ah[r];
            al8[mf] = *(const f16x8*)&Al[r];
        }
#pragma unroll
        for (int nf = 0; nf < 4; ++nf) {
            int r = (wn * 64 + nf * 16 + l15) * LDK + lk;
            bh8[nf] = *(const f16x8*)&Bh[r];
            bl8[nf] = *(const f16x8*)&Bl[r];
        }
#pragma unroll
        for (int mf = 0; mf < 4; ++mf)
#pragma unroll
            for (int nf = 0; nf < 4; ++nf) {
                accP[mf][nf] = __builtin_amdgcn_mfma_f32_16x16x32_f16(
                    ah[mf], bh8[nf], accP[mf][nf], 0, 0, 0);
                accQ[mf][nf] = __builtin_amdgcn_mfma_f32_16x16x32_f16(
                    ah[mf], bl8[nf], accQ[mf][nf], 0, 0, 0);
                accQ[mf][nf] = __builtin_amdgcn_mfma_f32_16x16x32_f16(
                    al8[mf], bh8[nf], accQ[mf][nf], 0, 0, 0);
            }
        __syncthreads();
    }

    // C/D layout: col = lane&15, row = (lane>>4)*4 + r   [m89-verified]
    int rsub = (lane >> 4) * 4;
#pragma unroll
    for (int nf = 0; nf < 4; ++nf) {
        int col = bn * GBN + wn * 64 + nf * 16 + l15;
        float bias = benc[col];
#pragma unroll
        for (int mf = 0; mf < 4; ++mf) {
            int rowb = bm * GBM + wm * 64 + mf * 16 + rsub;
#pragma unroll
            for (int r = 0; r < 4; ++r)
                H[(size_t)(rowb + r) * Ndim + col] =
                    (accP[mf][nf][r] + accQ[mf][nf][r] * (1.0f / 2048.0f)) * (1.0f / 1024.0f) + bias;
        }
    }
}

// ---------------------------------------------------------------------------
// K2: exact top-64 membership of energy = h*h per row (2048 cols).
// Radix-select (4 x 8-bit passes) on uint-ordered nonneg f32 keys; ties at the
// pivot filled by SMALLEST index (matches stable top_k). Output: 64 indices.
// ---------------------------------------------------------------------------
__global__ __launch_bounds__(256) void topk_kernel(
    const float* __restrict__ H, int* __restrict__ IDX) {
    int row = blockIdx.x, tid = threadIdx.x;
    __shared__ uint keys[2048];
    __shared__ uint hist[256];
    __shared__ uint sscan[256];
    __shared__ uint s_pd, s_r, s_n;
    const float* hrow = H + (size_t)row * Ndim;
    for (int i = tid; i < 2048; i += 256) {
        float h = hrow[i];
        keys[i] = __float_as_uint(h * h);
    }
    uint prefix = 0, pmask = 0, r = 64;
    __syncthreads();
    for (int shift = 24; shift >= 0; shift -= 8) {
        hist[tid] = 0;
        __syncthreads();
        for (int i = tid; i < 2048; i += 256) {
            uint k = keys[i];
            if ((k & pmask) == prefix) atomicAdd(&hist[(k >> shift) & 255], 1u);
        }
        __syncthreads();
        sscan[tid] = hist[tid];
        __syncthreads();
        for (int off = 1; off < 256; off <<= 1) {   // suffix-inclusive sum
            uint add = (tid + off < 256) ? sscan[tid + off] : 0;
            __syncthreads();
            sscan[tid] += add;
            __syncthreads();
        }
        uint mine = sscan[tid];
        uint above = (tid < 255) ? sscan[tid + 1] : 0;
        if (mine >= r && above < r) { s_pd = (uint)tid; s_r = r - above; }
        __syncthreads();
        prefix |= (s_pd << shift);
        pmask |= (255u << shift);
        r = s_r;
        __syncthreads();
    }
    uint P = prefix;
    uint cnt = 0;
    int base = tid * 8;
#pragma unroll
    for (int j = 0; j < 8; ++j) cnt += (keys[base + j] == P);
    sscan[tid] = cnt;
    if (tid == 0) s_n = 0;
    __syncthreads();
    for (int off = 1; off < 256; off <<= 1) {       // inclusive prefix sum
        uint v = (tid >= off) ? sscan[tid - off] : 0;
        __syncthreads();
        sscan[tid] += v;
        __syncthreads();
    }
    uint eqrank = (tid == 0) ? 0 : sscan[tid - 1];
    int* o = IDX + (size_t)row * 64;
    for (int j = 0; j < 8; ++j) {
        uint k = keys[base + j];
        bool sel = (k > P) || (k == P && eqrank < r);
        if (k == P) eqrank++;
        if (sel) { uint slot = atomicAdd(&s_n, 1u); o[slot] = base + j; }
    }
}

// ---------------------------------------------------------------------------
// K3: src_t[b][t] = last t'<=t with |theta-511|>256, else 0. (max-scan)
// ---------------------------------------------------------------------------
__global__ __launch_bounds__(256) void srct_kernel(
    const int* __restrict__ theta, int* __restrict__ srct) {
    __shared__ int cmax[256];
    int b = blockIdx.x, tid = threadIdx.x;
    const int* th = theta + b * 2048;
    int loc[8];
    int run = -1;
    int base = tid * 8;
#pragma unroll
    for (int j = 0; j < 8; ++j) {
        int d = th[base + j] - 511; d = d < 0 ? -d : d;
        if (d > 256) run = base + j;
        loc[j] = run;
    }
    cmax[tid] = run;
    __syncthreads();
    for (int off = 1; off < 256; off <<= 1) {
        int v = (tid >= off) ? cmax[tid - off] : -1;
        __syncthreads();
        if (v > cmax[tid]) cmax[tid] = v;
        __syncthreads();
    }
    int exc = (tid == 0) ? -1 : cmax[tid - 1];
    int* o = srct + b * 2048;
#pragma unroll
    for (int j = 0; j < 8; ++j) {
        int v = loc[j] > exc ? loc[j] : exc;
        o[base + j] = v < 0 ? 0 : v;
    }
}

// ---------------------------------------------------------------------------
// K4: per row: gather 64 h at idx[b,src_t], decoder out = sum hv*Wd + bd,
// then overwrite the H row with the f32 mask (H region == mask output region).
// out region (Xh/Xl scratch) is dead by now -> safe to overwrite with out.
// ---------------------------------------------------------------------------
__global__ __launch_bounds__(256) void out_kernel(
    float* Hm, const int* __restrict__ IDX, const int* __restrict__ SRCT,
    const float* __restrict__ Wd, const float* __restrict__ bd,
    float* __restrict__ outp) {
    int row = blockIdx.x, tid = threadIdx.x;
    int b = row >> 11;
    __shared__ int c[64];
    __shared__ float hv[64];
    __shared__ float mrow[2048];
    int s = SRCT[row];
    if (tid < 64) c[tid] = IDX[((size_t)((b << 11) + s)) * 64 + tid];
    float4 z = {0.f, 0.f, 0.f, 0.f};
    *(float4*)&mrow[tid * 8] = z;
    *(float4*)&mrow[tid * 8 + 4] = z;
    __syncthreads();
    if (tid < 64) {
        int ci = c[tid];
        hv[tid] = Hm[(size_t)row * Ndim + ci];
        mrow[ci] = 1.0f;
    }
    __syncthreads();
    int i0 = tid * 2;
    float a0 = bd[i0], a1 = bd[i0 + 1];
#pragma unroll 8
    for (int j = 0; j < 64; ++j) {
        float h = hv[j];
        float2 w = *(const float2*)(Wd + (size_t)c[j] * Kdim + i0);
        a0 += h * w.x;
        a1 += h * w.y;
    }
    *(float2*)(outp + (size_t)row * Kdim + i0) = make_float2(a0, a1);
    *(float4*)(Hm + (size_t)row * Ndim + tid * 8)     = *(float4*)&mrow[tid * 8];
    *(float4*)(Hm + (size_t)row * Ndim + tid * 8 + 4) = *(float4*)&mrow[tid * 8 + 4];
}

// ---------------------------------------------------------------------------
extern "C" void kernel_launch(void* const* d_in, const int* in_sizes, int n_in,
                              void* d_out, int out_size, void* d_ws, size_t ws_size,
                              hipStream_t stream) {
    const float* X  = (const float*)d_in[0];   // x f32 [8,2048,512]
    const int*   TH = (const int*)d_in[1];     // theta int32 [8,2048]
    const float* WE = (const float*)d_in[2];   // W_enc f32 [512,2048]
    const float* BE = (const float*)d_in[3];   // b_enc f32 [2048]
    const float* WD = (const float*)d_in[4];   // W_dec f32 [2048,512]
    const float* BD = (const float*)d_in[5];   // b_dec f32 [512]

    float* OUT = (float*)d_out;                          // [16384*512] f32
    float* H   = OUT + (size_t)Mrows * Kdim;             // mask region doubles as H

    // Xh/Xl overlay the out region (33.55MB == 2 x 16.78MB exactly); dead
    // before out_kernel writes out.
    _Float16* Xh = (_Float16*)OUT;
    _Float16* Xl = Xh + (size_t)Mrows * Kdim;

    char* ws = (char*)d_ws;
    _Float16* Wh  = (_Float16*)ws;                       // 2 MB
    _Float16* Wl  = (_Float16*)(ws + 2097152u);          // 2 MB
    int*      IDX = (int*)(ws + 4194304u);               // 4.19 MB
    int*      SRCT= (int*)(ws + 8388608u);               // 64 KB
    // total ws need: ~8.45 MB

    split_x_kernel<<<8192, 256, 0, stream>>>(X, Xh, Xl);
    split_w_kernel<<<dim3(64, 16), 256, 0, stream>>>(WE, Wh, Wl);
    gemm_split_kernel<<<dim3(Ndim / GBN, Mrows / GBM), 256, 0, stream>>>(
        Xh, Xl, Wh, Wl, BE, H);
    topk_kernel<<<Mrows, 256, 0, stream>>>(H, IDX);
    srct_kernel<<<8, 256, 0, stream>>>(TH, SRCT);
    out_kernel<<<Mrows, 256, 0, stream>>>(H, IDX, SRCT, WD, BD, OUT);
}

// Round 8
// 633.874 us; speedup vs baseline: 1.0447x; 1.0447x over previous
//
#include <hip/hip_runtime.h>

// B=8, T=2048, IDIM=512, HDIM=2048, CDIM=64, ENERGY_TH=256
// Device dtypes: all float tensors f32, theta int32.
// d_out = [out f32 8*2048*512 | mask f32 8*2048*2048]
//   - mask region doubles as H scratch (f32, 134MB), overwritten with mask at the end
//   - out  region doubles as Xh/Xl scratch (2x16.78MB f16), overwritten with out at the end
// d_ws: Wh 2MB | Wl 2MB | IDX 4.2MB | SRCT 64KB  (~8.45MB total)

typedef _Float16 f16x8 __attribute__((ext_vector_type(8)));
typedef _Float16 f16x4 __attribute__((ext_vector_type(4)));
typedef float    f32x4 __attribute__((ext_vector_type(4)));
typedef unsigned int uint;
typedef unsigned short ushort;

constexpr int Mrows = 16384;   // B*T
constexpr int Kdim  = 512;     // IDIM
constexpr int Ndim  = 2048;    // HDIM

__device__ __forceinline__ void gl16(const void* g, void* l) {
    __builtin_amdgcn_global_load_lds(
        (const __attribute__((address_space(1))) void*)g,
        (__attribute__((address_space(3))) void*)l, 16, 0, 0);
}

// ---------------------------------------------------------------------------
// K0a: split x (f32) -> xh = f16(x), xl = f16((x - xh)*2048)
// ---------------------------------------------------------------------------
__global__ __launch_bounds__(256) void split_x_kernel(
    const float* __restrict__ x, _Float16* __restrict__ xh, _Float16* __restrict__ xl) {
    int i = blockIdx.x * 256 + threadIdx.x;           // x4 floats
    float4 v = ((const float4*)x)[i];
    f16x4 h, l;
    float vv[4] = {v.x, v.y, v.z, v.w};
#pragma unroll
    for (int j = 0; j < 4; ++j) {
        _Float16 hj = (_Float16)vv[j];
        h[j] = hj;
        l[j] = (_Float16)((vv[j] - (float)hj) * 2048.0f);
    }
    *(f16x4*)(xh + i * 4) = h;
    *(f16x4*)(xl + i * 4) = l;
}

// ---------------------------------------------------------------------------
// K0b: transpose + split W_enc [512][2048] f32 -> Wh/Wl [2048][512] f16
// ---------------------------------------------------------------------------
__global__ __launch_bounds__(256) void split_w_kernel(
    const float* __restrict__ W, _Float16* __restrict__ Wh, _Float16* __restrict__ Wl) {
    __shared__ float T[32][33];
    int n0 = blockIdx.x * 32, k0 = blockIdx.y * 32;
    int tid = threadIdx.x;
    int c = tid & 31, r0 = tid >> 5;
#pragma unroll
    for (int i = 0; i < 4; ++i) {
        int r = r0 + 8 * i;
        T[r][c] = W[(size_t)(k0 + r) * Ndim + n0 + c];
    }
    __syncthreads();
#pragma unroll
    for (int i = 0; i < 4; ++i) {
        int r = r0 + 8 * i;                 // n-offset within tile
        float ws = T[c][r] * 1024.0f;
        _Float16 wh = (_Float16)ws;
        _Float16 wl = (_Float16)((ws - (float)wh) * 2048.0f);
        size_t o = (size_t)(n0 + r) * Kdim + k0 + c;
        Wh[o] = wh;
        Wl[o] = wl;
    }
}

// ---------------------------------------------------------------------------
// K1: H = x @ W_enc + b_enc via f16 split MFMA (3 terms), f32-accurate.
// 128x128 tile, BK=32, 4 waves (2x2), per-wave 64x64 = 4x4 frags of 16x16x32.
// Staging: global_load_lds (16B) into FRAGMENT-MAJOR LDS: per operand,
// 8 frag-blocks of 1KB; lane l's 16B slot in frag f holds
// global[(f*16 + (l&15))*512 + k0 + (l>>4)*8 .. +8]. Reads are then
// ds_read_b128 at base + lane*16 (conflict-free, uniform 8 accesses/bank).
// ---------------------------------------------------------------------------
__global__ __launch_bounds__(256) void gemm_split_kernel(
    const _Float16* __restrict__ Xh, const _Float16* __restrict__ Xl,
    const _Float16* __restrict__ Wh, const _Float16* __restrict__ Wl,
    const float* __restrict__ benc, float* __restrict__ H) {
    __shared__ _Float16 Ah[8 * 512], Al[8 * 512];    // 8KB each
    __shared__ _Float16 Bh[8 * 512], Bl[8 * 512];
    int tid = threadIdx.x;
    int bn = blockIdx.x, bm = blockIdx.y;
    int wave = tid >> 6, lane = tid & 63;
    int wm = wave >> 1, wn = wave & 1;

    f32x4 accP[4][4] = {};
    f32x4 accQ[4][4] = {};

    // per-lane global source offset for staging (frag-major permutation)
    int f0 = wave * 2;                                // this wave's frag pair
    int lrow = f0 * 16 + (lane & 15);                 // row within 128-tile
    int lcol = (lane >> 4) * 8;                       // k-offset (halves)
    const _Float16* gA_h = Xh + ((size_t)(bm * 128) + lrow) * Kdim + lcol;
    const _Float16* gA_l = Xl + ((size_t)(bm * 128) + lrow) * Kdim + lcol;
    const _Float16* gB_h = Wh + ((size_t)(bn * 128) + lrow) * Kdim + lcol;
    const _Float16* gB_l = Wl + ((size_t)(bn * 128) + lrow) * Kdim + lcol;
    // wave-uniform LDS dest bases (frag-blocks f0, f0+1)
    _Float16* lA_h = &Ah[f0 * 512];
    _Float16* lA_l = &Al[f0 * 512];
    _Float16* lB_h = &Bh[f0 * 512];
    _Float16* lB_l = &Bl[f0 * 512];
    constexpr int FSTRIDE = 16 * 512;                 // 16 rows in global (halves)

    for (int k0 = 0; k0 < Kdim; k0 += 32) {
        gl16(gA_h + k0, lA_h);  gl16(gA_h + k0 + FSTRIDE, lA_h + 512);
        gl16(gA_l + k0, lA_l);  gl16(gA_l + k0 + FSTRIDE, lA_l + 512);
        gl16(gB_h + k0, lB_h);  gl16(gB_h + k0 + FSTRIDE, lB_h + 512);
        gl16(gB_l + k0, lB_l);  gl16(gB_l + k0 + FSTRIDE, lB_l + 512);
        __syncthreads();

        f16x8 ah[4], al8[4], bh8[4], bl8[4];
#pragma unroll
        for (int mf = 0; mf < 4; ++mf) {
            int off = (wm * 4 + mf) * 512 + lane * 8;
            ah[mf]  = *(const f16x8*)&Ah[off];
            al8[mf] = *(const f16x8*)&Al[off];
        }
#pragma unroll
        for (int nf = 0; nf < 4; ++nf) {
            int off = (wn * 4 + nf) * 512 + lane * 8;
            bh8[nf] = *(const f16x8*)&Bh[off];
            bl8[nf] = *(const f16x8*)&Bl[off];
        }
#pragma unroll
        for (int mf = 0; mf < 4; ++mf)
#pragma unroll
            for (int nf = 0; nf < 4; ++nf) {
                accP[mf][nf] = __builtin_amdgcn_mfma_f32_16x16x32_f16(
                    ah[mf], bh8[nf], accP[mf][nf], 0, 0, 0);
                accQ[mf][nf] = __builtin_amdgcn_mfma_f32_16x16x32_f16(
                    ah[mf], bl8[nf], accQ[mf][nf], 0, 0, 0);
                accQ[mf][nf] = __builtin_amdgcn_mfma_f32_16x16x32_f16(
                    al8[mf], bh8[nf], accQ[mf][nf], 0, 0, 0);
            }
        __syncthreads();
    }

    // C/D layout: col = lane&15, row = (lane>>4)*4 + r   [m89-verified]
    int rsub = (lane >> 4) * 4;
#pragma unroll
    for (int nf = 0; nf < 4; ++nf) {
        int col = bn * 128 + wn * 64 + nf * 16 + (lane & 15);
        float bias = benc[col];
#pragma unroll
        for (int mf = 0; mf < 4; ++mf) {
            int rowb = bm * 128 + wm * 64 + mf * 16 + rsub;
#pragma unroll
            for (int r = 0; r < 4; ++r)
                H[(size_t)(rowb + r) * Ndim + col] =
                    (accP[mf][nf][r] + accQ[mf][nf][r] * (1.0f / 2048.0f)) * (1.0f / 1024.0f) + bias;
        }
    }
}

// ---------------------------------------------------------------------------
// K2: exact top-64 of energy=h*h per row via single-pass 2048-bin select.
// bin = key>>21 (monotone for non-negative f32). Pivot bin via coarse
// suffix-scan; exact ties resolved on pivot-bin candidates with packed
// sortkey (key desc, idx asc). Output: 64 indices (order irrelevant).
// ---------------------------------------------------------------------------
__global__ __launch_bounds__(256) void topk_kernel(
    const float* __restrict__ H, int* __restrict__ IDX) {
    int row = blockIdx.x, tid = threadIdx.x;
    __shared__ uint keys[2048];    // 8KB
    __shared__ uint hist[2048];    // 8KB
    __shared__ uint csum[256];     // 1KB
    __shared__ uint cand[2048];    // 8KB packed (key_low21<<11 | (2047-idx))
    __shared__ uint s_pivbin, s_r, s_n, s_nc;
    const float* hrow = H + (size_t)row * Ndim;

    int base = tid * 8;
#pragma unroll
    for (int j = 0; j < 8; j += 4) {
        float4 v = *(const float4*)(hrow + base + j);
        keys[base + j]     = __float_as_uint(v.x * v.x);
        keys[base + j + 1] = __float_as_uint(v.y * v.y);
        keys[base + j + 2] = __float_as_uint(v.z * v.z);
        keys[base + j + 3] = __float_as_uint(v.w * v.w);
        *(uint4*)&hist[base + j] = make_uint4(0, 0, 0, 0);
    }
    if (tid == 0) { s_n = 0; s_nc = 0; }
    __syncthreads();
#pragma unroll
    for (int j = 0; j < 8; ++j)
        atomicAdd(&hist[keys[base + j] >> 21], 1u);
    __syncthreads();
    // coarse sums: csum[t] = sum of hist[8t..8t+8)
    uint c = 0;
#pragma unroll
    for (int j = 0; j < 8; ++j) c += hist[base + j];
    csum[tid] = c;
    __syncthreads();
    // suffix-inclusive scan: csum[t] = count(bin >= 8t)
    for (int off = 1; off < 256; off <<= 1) {
        uint v = (tid + off < 256) ? csum[tid + off] : 0;
        __syncthreads();
        csum[tid] += v;
        __syncthreads();
    }
    uint above = (tid < 255) ? csum[tid + 1] : 0;
    if (csum[tid] >= 64 && above < 64) {
        uint cge = above;
        for (int b = 8 * tid + 7; b >= 8 * tid; --b) {
            cge += hist[b];
            if (cge >= 64) { s_pivbin = (uint)b; s_r = 64 - (cge - hist[b]); break; }
        }
    }
    __syncthreads();
    uint P = s_pivbin, r = s_r;
    int* o = IDX + (size_t)row * 64;
#pragma unroll
    for (int j = 0; j < 8; ++j) {
        uint k = keys[base + j];
        uint bin = k >> 21;
        if (bin > P) {
            o[atomicAdd(&s_n, 1u)] = base + j;
        } else if (bin == P) {
            cand[atomicAdd(&s_nc, 1u)] = ((k & 0x1FFFFFu) << 11) | (2047u - (uint)(base + j));
        }
    }
    __syncthreads();
    uint nc = s_nc;
    for (uint ci = tid; ci < nc; ci += 256) {
        uint me = cand[ci];
        uint rank = 0;
        for (uint j = 0; j < nc; ++j) rank += (cand[j] > me);
        if (rank < r) {
            o[atomicAdd(&s_n, 1u)] = 2047 - (int)(me & 0x7FFu);
        }
    }
}

// ---------------------------------------------------------------------------
// K3: src_t[b][t] = last t'<=t with |theta-511|>256, else 0. (max-scan)
// ---------------------------------------------------------------------------
__global__ __launch_bounds__(256) void srct_kernel(
    const int* __restrict__ theta, int* __restrict__ srct) {
    __shared__ int cmax[256];
    int b = blockIdx.x, tid = threadIdx.x;
    const int* th = theta + b * 2048;
    int loc[8];
    int run = -1;
    int base = tid * 8;
#pragma unroll
    for (int j = 0; j < 8; ++j) {
        int d = th[base + j] - 511; d = d < 0 ? -d : d;
        if (d > 256) run = base + j;
        loc[j] = run;
    }
    cmax[tid] = run;
    __syncthreads();
    for (int off = 1; off < 256; off <<= 1) {
        int v = (tid >= off) ? cmax[tid - off] : -1;
        __syncthreads();
        if (v > cmax[tid]) cmax[tid] = v;
        __syncthreads();
    }
    int exc = (tid == 0) ? -1 : cmax[tid - 1];
    int* o = srct + b * 2048;
#pragma unroll
    for (int j = 0; j < 8; ++j) {
        int v = loc[j] > exc ? loc[j] : exc;
        o[base + j] = v < 0 ? 0 : v;
    }
}

// ---------------------------------------------------------------------------
// K4: per row: gather 64 h at idx[b,src_t], decoder out = sum hv*Wd + bd,
// then overwrite the H row with the f32 mask (H region == mask output region).
// ---------------------------------------------------------------------------
__global__ __launch_bounds__(256) void out_kernel(
    float* Hm, const int* __restrict__ IDX, const int* __restrict__ SRCT,
    const float* __restrict__ Wd, const float* __restrict__ bd,
    float* __restrict__ outp) {
    int row = blockIdx.x, tid = threadIdx.x;
    int b = row >> 11;
    __shared__ int c[64];
    __shared__ float hv[64];
    __shared__ float mrow[2048];
    int s = SRCT[row];
    if (tid < 64) c[tid] = IDX[((size_t)((b << 11) + s)) * 64 + tid];
    float4 z = {0.f, 0.f, 0.f, 0.f};
    *(float4*)&mrow[tid * 8] = z;
    *(float4*)&mrow[tid * 8 + 4] = z;
    __syncthreads();
    if (tid < 64) {
        int ci = c[tid];
        hv[tid] = Hm[(size_t)row * Ndim + ci];
        mrow[ci] = 1.0f;
    }
    __syncthreads();
    int i0 = tid * 2;
    float a0 = bd[i0], a1 = bd[i0 + 1];
#pragma unroll 8
    for (int j = 0; j < 64; ++j) {
        float h = hv[j];
        float2 w = *(const float2*)(Wd + (size_t)c[j] * Kdim + i0);
        a0 += h * w.x;
        a1 += h * w.y;
    }
    *(float2*)(outp + (size_t)row * Kdim + i0) = make_float2(a0, a1);
    *(float4*)(Hm + (size_t)row * Ndim + tid * 8)     = *(float4*)&mrow[tid * 8];
    *(float4*)(Hm + (size_t)row * Ndim + tid * 8 + 4) = *(float4*)&mrow[tid * 8 + 4];
}

// ---------------------------------------------------------------------------
extern "C" void kernel_launch(void* const* d_in, const int* in_sizes, int n_in,
                              void* d_out, int out_size, void* d_ws, size_t ws_size,
                              hipStream_t stream) {
    const float* X  = (const float*)d_in[0];   // x f32 [8,2048,512]
    const int*   TH = (const int*)d_in[1];     // theta int32 [8,2048]
    const float* WE = (const float*)d_in[2];   // W_enc f32 [512,2048]
    const float* BE = (const float*)d_in[3];   // b_enc f32 [2048]
    const float* WD = (const float*)d_in[4];   // W_dec f32 [2048,512]
    const float* BD = (const float*)d_in[5];   // b_dec f32 [512]

    float* OUT = (float*)d_out;                          // [16384*512] f32
    float* H   = OUT + (size_t)Mrows * Kdim;             // mask region doubles as H

    // Xh/Xl overlay the out region (33.55MB == 2 x 16.78MB exactly); dead
    // before out_kernel writes out.
    _Float16* Xh = (_Float16*)OUT;
    _Float16* Xl = Xh + (size_t)Mrows * Kdim;

    char* ws = (char*)d_ws;
    _Float16* Wh  = (_Float16*)ws;                       // 2 MB
    _Float16* Wl  = (_Float16*)(ws + 2097152u);          // 2 MB
    int*      IDX = (int*)(ws + 4194304u);               // 4.19 MB
    int*      SRCT= (int*)(ws + 8388608u);               // 64 KB

    split_x_kernel<<<8192, 256, 0, stream>>>(X, Xh, Xl);
    split_w_kernel<<<dim3(64, 16), 256, 0, stream>>>(WE, Wh, Wl);
    gemm_split_kernel<<<dim3(Ndim / 128, Mrows / 128), 256, 0, stream>>>(
        Xh, Xl, Wh, Wl, BE, H);
    topk_kernel<<<Mrows, 256, 0, stream>>>(H, IDX);
    srct_kernel<<<8, 256, 0, stream>>>(TH, SRCT);
    out_kernel<<<Mrows, 256, 0, stream>>>(H, IDX, SRCT, WD, BD, OUT);
}

// Round 9
// 536.436 us; speedup vs baseline: 1.2345x; 1.1816x over previous
//
#include <hip/hip_runtime.h>

// B=8, T=2048, IDIM=512, HDIM=2048, CDIM=64, ENERGY_TH=256
// Device dtypes: all float tensors f32, theta int32.
// d_out = [out f32 8*2048*512 | mask f32 8*2048*2048]
//   - mask region doubles as H scratch; out region doubles as Xh/Xl scratch
// d_ws: Wh 2MB | Wl 2MB | IDX 4.2MB | SRCT 64KB  (~8.45MB total)

typedef _Float16 f16x8 __attribute__((ext_vector_type(8)));
typedef _Float16 f16x4 __attribute__((ext_vector_type(4)));
typedef float    f32x4 __attribute__((ext_vector_type(4)));
typedef unsigned int uint;
typedef unsigned short ushort;

constexpr int Mrows = 16384;   // B*T
constexpr int Kdim  = 512;     // IDIM
constexpr int Ndim  = 2048;    // HDIM

__device__ __forceinline__ void gl16(const void* g, void* l) {
    __builtin_amdgcn_global_load_lds(
        (const __attribute__((address_space(1))) void*)g,
        (__attribute__((address_space(3))) void*)l, 16, 0, 0);
}

// ---------------------------------------------------------------------------
// K0a: split x (f32) -> xh = f16(x), xl = f16((x - xh)*2048)
// ---------------------------------------------------------------------------
__global__ __launch_bounds__(256) void split_x_kernel(
    const float* __restrict__ x, _Float16* __restrict__ xh, _Float16* __restrict__ xl) {
    int i = blockIdx.x * 256 + threadIdx.x;           // x4 floats
    float4 v = ((const float4*)x)[i];
    f16x4 h, l;
    float vv[4] = {v.x, v.y, v.z, v.w};
#pragma unroll
    for (int j = 0; j < 4; ++j) {
        _Float16 hj = (_Float16)vv[j];
        h[j] = hj;
        l[j] = (_Float16)((vv[j] - (float)hj) * 2048.0f);
    }
    *(f16x4*)(xh + i * 4) = h;
    *(f16x4*)(xl + i * 4) = l;
}

// ---------------------------------------------------------------------------
// K0b: transpose + split W_enc [512][2048] f32 -> Wh/Wl [2048][512] f16
// ---------------------------------------------------------------------------
__global__ __launch_bounds__(256) void split_w_kernel(
    const float* __restrict__ W, _Float16* __restrict__ Wh, _Float16* __restrict__ Wl) {
    __shared__ float T[32][33];
    int n0 = blockIdx.x * 32, k0 = blockIdx.y * 32;
    int tid = threadIdx.x;
    int c = tid & 31, r0 = tid >> 5;
#pragma unroll
    for (int i = 0; i < 4; ++i) {
        int r = r0 + 8 * i;
        T[r][c] = W[(size_t)(k0 + r) * Ndim + n0 + c];
    }
    __syncthreads();
#pragma unroll
    for (int i = 0; i < 4; ++i) {
        int r = r0 + 8 * i;                 // n-offset within tile
        float ws = T[c][r] * 1024.0f;
        _Float16 wh = (_Float16)ws;
        _Float16 wl = (_Float16)((ws - (float)wh) * 2048.0f);
        size_t o = (size_t)(n0 + r) * Kdim + k0 + c;
        Wh[o] = wh;
        Wl[o] = wl;
    }
}

// ---------------------------------------------------------------------------
// K1: H = x @ W_enc + b_enc via f16 split MFMA (3 terms), f32-accurate.
// 128x128 tile, BK=32, 4 waves (2x2), per-wave 64x64 = 4x4 frags of 16x16x32.
// Fragment-major LDS staging via global_load_lds (conflict-free reads), now
// DOUBLE-BUFFERED: per iteration, issue next tile's 8 gl16 per wave FIRST,
// then ds_read+MFMA current tile, then one __syncthreads (drains vmcnt ->
// prefetch landed; barrier -> safe to overwrite the other buffer next iter).
// XCD-chunked block swizzle (2048 blocks, 8 XCDs, bijective).
// ---------------------------------------------------------------------------
__global__ __launch_bounds__(256) void gemm_split_kernel(
    const _Float16* __restrict__ Xh, const _Float16* __restrict__ Xl,
    const _Float16* __restrict__ Wh, const _Float16* __restrict__ Wl,
    const float* __restrict__ benc, float* __restrict__ H) {
    __shared__ _Float16 Ah[2][8 * 512], Al[2][8 * 512];   // 16KB each pair
    __shared__ _Float16 Bh[2][8 * 512], Bl[2][8 * 512];   // total 64KB
    int tid = threadIdx.x;
    // XCD swizzle: consecutive orig ids round-robin XCDs; give each XCD a
    // contiguous 256-block chunk (= 16 consecutive bm bands, all bn).
    int orig = blockIdx.x;
    int wgid = (orig & 7) * 256 + (orig >> 3);
    int bn = wgid & 15;                    // Ndim/128 = 16
    int bm = wgid >> 4;                    // Mrows/128 = 128
    int wave = tid >> 6, lane = tid & 63;
    int wm = wave >> 1, wn = wave & 1;

    f32x4 accP[4][4] = {};
    f32x4 accQ[4][4] = {};

    // per-lane global source (frag-major permutation): lane l of frag f holds
    // rows f*16+(l&15), k-halves (l>>4)*8 .. +8
    int f0 = wave * 2;                                // this wave stages frags f0,f0+1
    int lrow = f0 * 16 + (lane & 15);
    int lcol = (lane >> 4) * 8;
    const _Float16* gA_h = Xh + ((size_t)(bm * 128) + lrow) * Kdim + lcol;
    const _Float16* gA_l = Xl + ((size_t)(bm * 128) + lrow) * Kdim + lcol;
    const _Float16* gB_h = Wh + ((size_t)(bn * 128) + lrow) * Kdim + lcol;
    const _Float16* gB_l = Wl + ((size_t)(bn * 128) + lrow) * Kdim + lcol;
    constexpr int FSTRIDE = 16 * 512;                 // 16 global rows (halves)
    int ldst = f0 * 512;                              // wave-uniform LDS frag base

#define STAGE(buf, kof)                                                     \
    do {                                                                    \
        gl16(gA_h + (kof), &Ah[buf][ldst]);                                 \
        gl16(gA_h + (kof) + FSTRIDE, &Ah[buf][ldst + 512]);                 \
        gl16(gA_l + (kof), &Al[buf][ldst]);                                 \
        gl16(gA_l + (kof) + FSTRIDE, &Al[buf][ldst + 512]);                 \
        gl16(gB_h + (kof), &Bh[buf][ldst]);                                 \
        gl16(gB_h + (kof) + FSTRIDE, &Bh[buf][ldst + 512]);                 \
        gl16(gB_l + (kof), &Bl[buf][ldst]);                                 \
        gl16(gB_l + (kof) + FSTRIDE, &Bl[buf][ldst + 512]);                 \
    } while (0)

#define COMPUTE(buf)                                                        \
    do {                                                                    \
        f16x8 ah[4], al8[4], bh8[4], bl8[4];                                \
        _Pragma("unroll")                                                   \
        for (int mf = 0; mf < 4; ++mf) {                                    \
            int off = (wm * 4 + mf) * 512 + lane * 8;                       \
            ah[mf]  = *(const f16x8*)&Ah[buf][off];                         \
            al8[mf] = *(const f16x8*)&Al[buf][off];                         \
        }                                                                   \
        _Pragma("unroll")                                                   \
        for (int nf = 0; nf < 4; ++nf) {                                    \
            int off = (wn * 4 + nf) * 512 + lane * 8;                       \
            bh8[nf] = *(const f16x8*)&Bh[buf][off];                         \
            bl8[nf] = *(const f16x8*)&Bl[buf][off];                         \
        }                                                                   \
        _Pragma("unroll")                                                   \
        for (int mf = 0; mf < 4; ++mf)                                      \
            _Pragma("unroll")                                               \
            for (int nf = 0; nf < 4; ++nf) {                                \
                accP[mf][nf] = __builtin_amdgcn_mfma_f32_16x16x32_f16(      \
                    ah[mf], bh8[nf], accP[mf][nf], 0, 0, 0);                \
                accQ[mf][nf] = __builtin_amdgcn_mfma_f32_16x16x32_f16(      \
                    ah[mf], bl8[nf], accQ[mf][nf], 0, 0, 0);                \
                accQ[mf][nf] = __builtin_amdgcn_mfma_f32_16x16x32_f16(      \
                    al8[mf], bh8[nf], accQ[mf][nf], 0, 0, 0);               \
            }                                                               \
    } while (0)

    STAGE(0, 0);
    __syncthreads();                       // prologue latency paid once
    int cur = 0;
#pragma unroll 1
    for (int t = 0; t < 15; ++t) {
        STAGE(cur ^ 1, (t + 1) * 32);      // prefetch next tile (in flight
        COMPUTE(cur);                      //  during these 48 MFMAs)
        __syncthreads();                   // vmcnt drain + barrier
        cur ^= 1;
    }
    COMPUTE(cur);                          // last tile, no prefetch

    // C/D layout: col = lane&15, row = (lane>>4)*4 + r   [m89-verified]
    int rsub = (lane >> 4) * 4;
#pragma unroll
    for (int nf = 0; nf < 4; ++nf) {
        int col = bn * 128 + wn * 64 + nf * 16 + (lane & 15);
        float bias = benc[col];
#pragma unroll
        for (int mf = 0; mf < 4; ++mf) {
            int rowb = bm * 128 + wm * 64 + mf * 16 + rsub;
#pragma unroll
            for (int r = 0; r < 4; ++r)
                H[(size_t)(rowb + r) * Ndim + col] =
                    (accP[mf][nf][r] + accQ[mf][nf][r] * (1.0f / 2048.0f)) * (1.0f / 1024.0f) + bias;
        }
    }
#undef STAGE
#undef COMPUTE
}

// ---------------------------------------------------------------------------
// K2: exact top-64 of energy=h*h per row via single-pass 2048-bin select.
// ---------------------------------------------------------------------------
__global__ __launch_bounds__(256) void topk_kernel(
    const float* __restrict__ H, int* __restrict__ IDX) {
    int row = blockIdx.x, tid = threadIdx.x;
    __shared__ uint keys[2048];
    __shared__ uint hist[2048];
    __shared__ uint csum[256];
    __shared__ uint cand[2048];    // packed (key_low21<<11 | (2047-idx))
    __shared__ uint s_pivbin, s_r, s_n, s_nc;
    const float* hrow = H + (size_t)row * Ndim;

    int base = tid * 8;
#pragma unroll
    for (int j = 0; j < 8; j += 4) {
        float4 v = *(const float4*)(hrow + base + j);
        keys[base + j]     = __float_as_uint(v.x * v.x);
        keys[base + j + 1] = __float_as_uint(v.y * v.y);
        keys[base + j + 2] = __float_as_uint(v.z * v.z);
        keys[base + j + 3] = __float_as_uint(v.w * v.w);
        *(uint4*)&hist[base + j] = make_uint4(0, 0, 0, 0);
    }
    if (tid == 0) { s_n = 0; s_nc = 0; }
    __syncthreads();
#pragma unroll
    for (int j = 0; j < 8; ++j)
        atomicAdd(&hist[keys[base + j] >> 21], 1u);
    __syncthreads();
    uint c = 0;
#pragma unroll
    for (int j = 0; j < 8; ++j) c += hist[base + j];
    csum[tid] = c;
    __syncthreads();
    for (int off = 1; off < 256; off <<= 1) {   // suffix-inclusive scan
        uint v = (tid + off < 256) ? csum[tid + off] : 0;
        __syncthreads();
        csum[tid] += v;
        __syncthreads();
    }
    uint above = (tid < 255) ? csum[tid + 1] : 0;
    if (csum[tid] >= 64 && above < 64) {
        uint cge = above;
        for (int b = 8 * tid + 7; b >= 8 * tid; --b) {
            cge += hist[b];
            if (cge >= 64) { s_pivbin = (uint)b; s_r = 64 - (cge - hist[b]); break; }
        }
    }
    __syncthreads();
    uint P = s_pivbin, r = s_r;
    int* o = IDX + (size_t)row * 64;
#pragma unroll
    for (int j = 0; j < 8; ++j) {
        uint k = keys[base + j];
        uint bin = k >> 21;
        if (bin > P) {
            o[atomicAdd(&s_n, 1u)] = base + j;
        } else if (bin == P) {
            cand[atomicAdd(&s_nc, 1u)] = ((k & 0x1FFFFFu) << 11) | (2047u - (uint)(base + j));
        }
    }
    __syncthreads();
    uint nc = s_nc;
    for (uint ci = tid; ci < nc; ci += 256) {
        uint me = cand[ci];
        uint rank = 0;
        for (uint j = 0; j < nc; ++j) rank += (cand[j] > me);
        if (rank < r) {
            o[atomicAdd(&s_n, 1u)] = 2047 - (int)(me & 0x7FFu);
        }
    }
}

// ---------------------------------------------------------------------------
// K3: src_t[b][t] = last t'<=t with |theta-511|>256, else 0. (max-scan)
// ---------------------------------------------------------------------------
__global__ __launch_bounds__(256) void srct_kernel(
    const int* __restrict__ theta, int* __restrict__ srct) {
    __shared__ int cmax[256];
    int b = blockIdx.x, tid = threadIdx.x;
    const int* th = theta + b * 2048;
    int loc[8];
    int run = -1;
    int base = tid * 8;
#pragma unroll
    for (int j = 0; j < 8; ++j) {
        int d = th[base + j] - 511; d = d < 0 ? -d : d;
        if (d > 256) run = base + j;
        loc[j] = run;
    }
    cmax[tid] = run;
    __syncthreads();
    for (int off = 1; off < 256; off <<= 1) {
        int v = (tid >= off) ? cmax[tid - off] : -1;
        __syncthreads();
        if (v > cmax[tid]) cmax[tid] = v;
        __syncthreads();
    }
    int exc = (tid == 0) ? -1 : cmax[tid - 1];
    int* o = srct + b * 2048;
#pragma unroll
    for (int j = 0; j < 8; ++j) {
        int v = loc[j] > exc ? loc[j] : exc;
        o[base + j] = v < 0 ? 0 : v;
    }
}

// ---------------------------------------------------------------------------
// K4: per row: gather 64 h at idx[b,src_t], decoder out = sum hv*Wd + bd,
// then overwrite the H row with the f32 mask (H region == mask output region).
// ---------------------------------------------------------------------------
__global__ __launch_bounds__(256) void out_kernel(
    float* Hm, const int* __restrict__ IDX, const int* __restrict__ SRCT,
    const float* __restrict__ Wd, const float* __restrict__ bd,
    float* __restrict__ outp) {
    int row = blockIdx.x, tid = threadIdx.x;
    int b = row >> 11;
    __shared__ int c[64];
    __shared__ float hv[64];
    __shared__ float mrow[2048];
    int s = SRCT[row];
    if (tid < 64) c[tid] = IDX[((size_t)((b << 11) + s)) * 64 + tid];
    float4 z = {0.f, 0.f, 0.f, 0.f};
    *(float4*)&mrow[tid * 8] = z;
    *(float4*)&mrow[tid * 8 + 4] = z;
    __syncthreads();
    if (tid < 64) {
        int ci = c[tid];
        hv[tid] = Hm[(size_t)row * Ndim + ci];
        mrow[ci] = 1.0f;
    }
    __syncthreads();
    int i0 = tid * 2;
    float a0 = bd[i0], a1 = bd[i0 + 1];
#pragma unroll 8
    for (int j = 0; j < 64; ++j) {
        float h = hv[j];
        float2 w = *(const float2*)(Wd + (size_t)c[j] * Kdim + i0);
        a0 += h * w.x;
        a1 += h * w.y;
    }
    *(float2*)(outp + (size_t)row * Kdim + i0) = make_float2(a0, a1);
    *(float4*)(Hm + (size_t)row * Ndim + tid * 8)     = *(float4*)&mrow[tid * 8];
    *(float4*)(Hm + (size_t)row * Ndim + tid * 8 + 4) = *(float4*)&mrow[tid * 8 + 4];
}

// ---------------------------------------------------------------------------
extern "C" void kernel_launch(void* const* d_in, const int* in_sizes, int n_in,
                              void* d_out, int out_size, void* d_ws, size_t ws_size,
                              hipStream_t stream) {
    const float* X  = (const float*)d_in[0];   // x f32 [8,2048,512]
    const int*   TH = (const int*)d_in[1];     // theta int32 [8,2048]
    const float* WE = (const float*)d_in[2];   // W_enc f32 [512,2048]
    const float* BE = (const float*)d_in[3];   // b_enc f32 [2048]
    const float* WD = (const float*)d_in[4];   // W_dec f32 [2048,512]
    const float* BD = (const float*)d_in[5];   // b_dec f32 [512]

    float* OUT = (float*)d_out;                          // [16384*512] f32
    float* H   = OUT + (size_t)Mrows * Kdim;             // mask region doubles as H

    _Float16* Xh = (_Float16*)OUT;                       // out region scratch
    _Float16* Xl = Xh + (size_t)Mrows * Kdim;

    char* ws = (char*)d_ws;
    _Float16* Wh  = (_Float16*)ws;                       // 2 MB
    _Float16* Wl  = (_Float16*)(ws + 2097152u);          // 2 MB
    int*      IDX = (int*)(ws + 4194304u);               // 4.19 MB
    int*      SRCT= (int*)(ws + 8388608u);               // 64 KB

    split_x_kernel<<<8192, 256, 0, stream>>>(X, Xh, Xl);
    split_w_kernel<<<dim3(64, 16), 256, 0, stream>>>(WE, Wh, Wl);
    gemm_split_kernel<<<2048, 256, 0, stream>>>(Xh, Xl, Wh, Wl, BE, H);
    topk_kernel<<<Mrows, 256, 0, stream>>>(H, IDX);
    srct_kernel<<<8, 256, 0, stream>>>(TH, SRCT);
    out_kernel<<<Mrows, 256, 0, stream>>>(H, IDX, SRCT, WD, BD, OUT);
}